// Round 12
// baseline (1359.889 us; speedup 1.0000x reference)
//
#include <hip/hip_runtime.h>

#define TT 2048
#define HH 64
#define II 6
#define OO 6
#define NTHR 512   // 8 waves: 4 A-waves (layer0 + FC1), 4 B-waves (layer1 fused + FC2)

typedef float    f32x4 __attribute__((ext_vector_type(4)));
typedef float    f32x2 __attribute__((ext_vector_type(2)));
typedef _Float16 f16x8 __attribute__((ext_vector_type(8)));

__device__ __forceinline__ float fast_sig(float v) {
    return __builtin_amdgcn_rcpf(1.0f + __expf(-v));
}
__device__ __forceinline__ float fast_tanh(float v) {
    return 1.0f - 2.0f * __builtin_amdgcn_rcpf(__expf(2.0f * v) + 1.0f);
}

#define MFMA(a, b, c) __builtin_amdgcn_mfma_f32_16x16x32_f16((a), (b), (c), 0, 0, 0)

// LDS-only barrier: global loads/stores stay in flight across it.
#define LGKM_BARRIER() asm volatile("s_waitcnt lgkmcnt(0)\ns_barrier" ::: "memory")

__global__
__attribute__((amdgpu_flat_work_group_size(NTHR, NTHR)))
__attribute__((amdgpu_waves_per_eu(2, 2)))
void lstm_mfma_kernel(const float* __restrict__ x,
                      const float* __restrict__ Wih0, const float* __restrict__ Whh0,
                      const float* __restrict__ b0,
                      const float* __restrict__ Wih1, const float* __restrict__ Whh1,
                      const float* __restrict__ b1,
                      const float* __restrict__ W1, const float* __restrict__ bf1,
                      const float* __restrict__ W2, const float* __restrict__ bf2,
                      float* __restrict__ out)
{
    const int row  = blockIdx.x;      // one batch row per block
    const int tid  = threadIdx.x;
    const int wid  = tid >> 6;        // wave id 0..7
    const int lane = tid & 63;
    const int n    = lane & 15;       // MFMA col-lane (B-col / D-col)
    const int q    = lane >> 4;       // k-group: lane holds k = 8q..8q+7 (+32 for hi)
    const bool isA = wid < 4;
    const int  w   = isA ? wid : wid - 4;   // role-local wave index 0..3

    // h0 needs 4 slots: A writes t&3, A reads (t+3)&3 (=t-1), B reads (t+2)&3 (=t-2)
    __shared__ __attribute__((aligned(16))) _Float16 H0[4][HH];
    __shared__ __attribute__((aligned(16))) _Float16 H1[2][HH];
    __shared__ __attribute__((aligned(16))) _Float16 Rb[2][HH];

    if (tid < HH) {
        H0[0][tid] = (_Float16)0.f; H0[1][tid] = (_Float16)0.f;
        H0[2][tid] = (_Float16)0.f; H0[3][tid] = (_Float16)0.f;
        H1[0][tid] = (_Float16)0.f; H1[1][tid] = (_Float16)0.f;
        Rb[0][tid] = (_Float16)0.f; Rb[1][tid] = (_Float16)0.f;
    }

    // elem i <-> k = kbase + 8q + i (same map for A-frag reads, so it cancels)
    auto mk = [&](const float* W, int r, int ld, int kbase, int kmax, bool rok) {
        f16x8 f;
        #pragma unroll
        for (int i = 0; i < 8; ++i) {
            int kk = kbase + 8 * q + i;
            f[i] = (rok && kk < kmax) ? (_Float16)W[r * ld + kk] : (_Float16)0.f;
        }
        return f;
    };
    auto splat = [](float v) { f32x4 r = {v, v, v, v}; return r; };

    // ---- weight frags + loop-invariant bias C-vectors
    f16x8 frag[16], fragX[2];
    f32x4 biasv[4], biasX;

    if (isA) {
        #pragma unroll
        for (int g = 0; g < 4; ++g) {           // layer0 gates: 3-chunk chain
            const int r0 = g * HH + 16 * w + n; // gate row (i,f,g,o stacked)
            frag[g * 3 + 0] = mk(Whh0, r0, HH, 0,  HH, true);
            frag[g * 3 + 1] = mk(Whh0, r0, HH, 32, HH, true);
            frag[g * 3 + 2] = mk(Wih0, r0, II, 0,  II, true);  // x-chunk (k>=6 zero)
            biasv[g] = splat(b0[r0]);
        }
        const int rf = 16 * w + n;              // FC1 row
        fragX[0] = mk(W1, rf, HH, 0,  HH, true);
        fragX[1] = mk(W1, rf, HH, 32, HH, true);
        biasX = splat(bf1[rf]);
        #pragma unroll
        for (int i = 12; i < 16; ++i) frag[i] = frag[0];   // unused
    } else {
        #pragma unroll
        for (int g = 0; g < 4; ++g) {           // layer1 gates: fused 4-chunk chain
            const int r0 = g * HH + 16 * w + n;
            frag[g * 4 + 0] = mk(Wih1, r0, HH, 0,  HH, true);   // @ h0[t-2]
            frag[g * 4 + 1] = mk(Wih1, r0, HH, 32, HH, true);
            frag[g * 4 + 2] = mk(Whh1, r0, HH, 0,  HH, true);   // @ h1[t-3]
            frag[g * 4 + 3] = mk(Whh1, r0, HH, 32, HH, true);
            biasv[g] = splat(b1[r0]);
        }
        fragX[0] = mk(W2, n, HH, 0,  HH, n < OO);               // FC2 (w0 only uses)
        fragX[1] = mk(W2, n, HH, 32, HH, n < OO);
        biasX = splat((n < OO) ? bf2[n] : 0.f);
    }

    // x is register-carried; opaque VGPR pointer forces vector (vmcnt) loads
    const float* xrow = x + (size_t)row * TT * II;
    {
        unsigned long long p = (unsigned long long)xrow;
        asm volatile("" : "+v"(p));
        xrow = (const float*)p;
    }
    f32x4 xc03 = {0.f, 0.f, 0.f, 0.f};
    f32x2 xc45 = {0.f, 0.f};
    if (isA) {
        xc03 = *reinterpret_cast<const f32x4*>(xrow);
        xc45 = *reinterpret_cast<const f32x2*>(xrow + 4);
    }

    float* outrow = out + (size_t)row * TT * OO;
    float cst = 0.f;   // cell state: A lanes 0-15 hold c0[unit 16w+n]; B: c1

    __syncthreads();   // full barrier once, before the loop

    // pipeline: A@t: layer0 step t (h0[t-1]) + FC1 s3=t-3 (h1[t-3], Rb write)
    //           B@t: layer1 step s2=t-2 (h0[t-2], h1[t-3]) + FC2 s4=t-4 (Rb read)
    for (int t = 0; t <= TT + 3; ++t) {
        const int slp2 = (t + 1) & 1;   // h1[t-3] slot; Rb write slot
        const int slc2 = t & 1;         // h1 write slot (s2); Rb read slot (s4)

        if (isA) {
            // issue x[t+1] prefetch FIRST (vmcnt-lazy, ~1 iter of cover)
            const int tn = (t + 1 < TT) ? t + 1 : TT - 1;
            const float* xp = xrow + (size_t)tn * II;
            f32x4 xn03 = *reinterpret_cast<const f32x4*>(xp);
            f32x2 xn45 = *reinterpret_cast<const f32x2*>(xp + 4);

            // broadcast A-frags: h0[t-1]
            const f16x8 a0 = *reinterpret_cast<const f16x8*>(&H0[(t + 3) & 3][8 * q]);
            const f16x8 a1 = *reinterpret_cast<const f16x8*>(&H0[(t + 3) & 3][32 + 8 * q]);
            f16x8 a2;    // x[t] from regs (all lanes hold real x; k>=6 zero on B-side)
            a2[0] = (_Float16)xc03[0]; a2[1] = (_Float16)xc03[1];
            a2[2] = (_Float16)xc03[2]; a2[3] = (_Float16)xc03[3];
            a2[4] = (_Float16)xc45[0]; a2[5] = (_Float16)xc45[1];
            a2[6] = (_Float16)0.f;     a2[7] = (_Float16)0.f;

            f32x4 d0, d1, d2, d3;
            #pragma unroll
            for (int g = 0; g < 4; ++g) {
                f32x4 acc = MFMA(a0, frag[g * 3 + 0], biasv[g]);  // bias as C-init
                acc = MFMA(a1, frag[g * 3 + 1], acc);
                acc = MFMA(a2, frag[g * 3 + 2], acc);
                if (g == 0) d0 = acc; else if (g == 1) d1 = acc;
                else if (g == 2) d2 = acc; else d3 = acc;
            }
            if (t < TT) {
                float i_ = fast_sig(d0[0]), f_ = fast_sig(d1[0]);
                float g_ = fast_tanh(d2[0]), o_ = fast_sig(d3[0]);
                cst = f_ * cst + i_ * g_;
                float h = o_ * fast_tanh(cst);
                if (lane < 16) H0[t & 3][16 * w + lane] = (_Float16)h;
            }
            {   // FC1: relu(W1 . h1[s3] + bf1) -> Rb
                const int s3 = t - 3;
                const f16x8 b0f = *reinterpret_cast<const f16x8*>(&H1[slp2][8 * q]);
                const f16x8 b1f = *reinterpret_cast<const f16x8*>(&H1[slp2][32 + 8 * q]);
                f32x4 acc = MFMA(b0f, fragX[0], biasX);
                acc = MFMA(b1f, fragX[1], acc);
                if (s3 >= 0 && s3 < TT && lane < 16)
                    Rb[slp2][16 * w + lane] = (_Float16)fmaxf(acc[0], 0.f);
            }
            xc03 = xn03;   // vmcnt wait lands at a2-build next iter
            xc45 = xn45;
        } else {
            const int s2 = t - 2, s4 = t - 4;
            // fused layer1 chain: (b1) + Wih1.h0[s2] + Whh1.h1[s2-1]
            const f16x8 h00 = *reinterpret_cast<const f16x8*>(&H0[(t + 2) & 3][8 * q]);
            const f16x8 h01 = *reinterpret_cast<const f16x8*>(&H0[(t + 2) & 3][32 + 8 * q]);
            const f16x8 a0  = *reinterpret_cast<const f16x8*>(&H1[slp2][8 * q]);
            const f16x8 a1  = *reinterpret_cast<const f16x8*>(&H1[slp2][32 + 8 * q]);
            f32x4 d0, d1, d2, d3;
            #pragma unroll
            for (int g = 0; g < 4; ++g) {
                f32x4 acc = MFMA(h00, frag[g * 4 + 0], biasv[g]);
                acc = MFMA(h01, frag[g * 4 + 1], acc);
                acc = MFMA(a0,  frag[g * 4 + 2], acc);
                acc = MFMA(a1,  frag[g * 4 + 3], acc);
                if (g == 0) d0 = acc; else if (g == 1) d1 = acc;
                else if (g == 2) d2 = acc; else d3 = acc;
            }
            if (s2 >= 0 && s2 < TT) {
                float i_ = fast_sig(d0[0]), f_ = fast_sig(d1[0]);
                float g_ = fast_tanh(d2[0]), o_ = fast_sig(d3[0]);
                cst = f_ * cst + i_ * g_;
                float h = o_ * fast_tanh(cst);
                if (lane < 16) H1[slc2][16 * w + lane] = (_Float16)h;
            }
            if (w == 0) {   // FC2: W2 . r[s4] + bf2 -> out (store drains lazily)
                const f16x8 r0 = *reinterpret_cast<const f16x8*>(&Rb[slc2][8 * q]);
                const f16x8 r1 = *reinterpret_cast<const f16x8*>(&Rb[slc2][32 + 8 * q]);
                f32x4 acc = MFMA(r0, fragX[0], biasX);
                acc = MFMA(r1, fragX[1], acc);
                if (s4 >= 0 && s4 < TT && lane < OO)
                    outrow[(size_t)s4 * OO + lane] = acc[0];
            }
        }
        LGKM_BARRIER();   // LDS-only drain; global ops stay in flight
    }
}

extern "C" void kernel_launch(void* const* d_in, const int* in_sizes, int n_in,
                              void* d_out, int out_size, void* d_ws, size_t ws_size,
                              hipStream_t stream) {
    const float* xp   = (const float*)d_in[0];
    const float* Wih0 = (const float*)d_in[1];
    const float* Whh0 = (const float*)d_in[2];
    const float* b0   = (const float*)d_in[3];
    const float* Wih1 = (const float*)d_in[4];
    const float* Whh1 = (const float*)d_in[5];
    const float* b1   = (const float*)d_in[6];
    const float* W1   = (const float*)d_in[7];
    const float* bf1  = (const float*)d_in[8];
    const float* W2   = (const float*)d_in[9];
    const float* bf2  = (const float*)d_in[10];
    float* outp = (float*)d_out;

    lstm_mfma_kernel<<<dim3(256), dim3(NTHR), 0, stream>>>(
        xp, Wih0, Whh0, b0, Wih1, Whh1, b1, W1, bf1, W2, bf2, outp);
}

// Round 13
// 1139.351 us; speedup vs baseline: 1.1936x; 1.1936x over previous
//
#include <hip/hip_runtime.h>

#define TT 2048
#define HH 64
#define II 6
#define OO 6
#define NTHR 512   // 8 waves: 4 A-waves (layer0 + FC1), 4 B-waves (layer1 fused + FC2)

typedef float    f32x4 __attribute__((ext_vector_type(4)));
typedef float    f32x2 __attribute__((ext_vector_type(2)));
typedef _Float16 f16x8 __attribute__((ext_vector_type(8)));

__device__ __forceinline__ float fast_sig(float v) {
    return __builtin_amdgcn_rcpf(1.0f + __expf(-v));
}
__device__ __forceinline__ float fast_tanh(float v) {
    return 1.0f - 2.0f * __builtin_amdgcn_rcpf(__expf(2.0f * v) + 1.0f);
}

#define MFMA(a, b, c) __builtin_amdgcn_mfma_f32_16x16x32_f16((a), (b), (c), 0, 0, 0)

// LDS-only barrier: global loads/stores stay in flight across it.
#define LGKM_BARRIER() asm volatile("s_waitcnt lgkmcnt(0)\ns_barrier" ::: "memory")

__global__
__attribute__((amdgpu_flat_work_group_size(NTHR, NTHR)))
__attribute__((amdgpu_waves_per_eu(2, 2)))
void lstm_mfma_kernel(const float* __restrict__ x,
                      const float* __restrict__ Wih0, const float* __restrict__ Whh0,
                      const float* __restrict__ b0,
                      const float* __restrict__ Wih1, const float* __restrict__ Whh1,
                      const float* __restrict__ b1,
                      const float* __restrict__ W1, const float* __restrict__ bf1,
                      const float* __restrict__ W2, const float* __restrict__ bf2,
                      float* __restrict__ out)
{
    const int row  = blockIdx.x;      // one batch row per block
    const int tid  = threadIdx.x;
    const int wid  = tid >> 6;        // wave id 0..7
    const int lane = tid & 63;
    const int n    = lane & 15;       // MFMA col-lane (B-col / D-col)
    const int q    = lane >> 4;       // k-group: lane holds k = 8q..8q+7 (+32 for hi)
    const bool isA = wid < 4;
    const int  w   = isA ? wid : wid - 4;   // role-local wave index 0..3

    // h0 needs 4 slots: A writes t&3, A reads (t+3)&3 (=t-1), B reads (t+2)&3 (=t-2)
    __shared__ __attribute__((aligned(16))) _Float16 H0[4][HH];
    __shared__ __attribute__((aligned(16))) _Float16 H1[2][HH];
    __shared__ __attribute__((aligned(16))) _Float16 Rb[2][HH];

    if (tid < HH) {
        H0[0][tid] = (_Float16)0.f; H0[1][tid] = (_Float16)0.f;
        H0[2][tid] = (_Float16)0.f; H0[3][tid] = (_Float16)0.f;
        H1[0][tid] = (_Float16)0.f; H1[1][tid] = (_Float16)0.f;
        Rb[0][tid] = (_Float16)0.f; Rb[1][tid] = (_Float16)0.f;
    }

    // elem i <-> k = kbase + 8q + i (same map for A-frag reads, so it cancels)
    auto mk = [&](const float* W, int r, int ld, int kbase, int kmax, bool rok) {
        f16x8 f;
        #pragma unroll
        for (int i = 0; i < 8; ++i) {
            int kk = kbase + 8 * q + i;
            f[i] = (rok && kk < kmax) ? (_Float16)W[r * ld + kk] : (_Float16)0.f;
        }
        return f;
    };
    auto splat = [](float v) { f32x4 r = {v, v, v, v}; return r; };

    // ---- weight frags + loop-invariant bias C-vectors
    f16x8 frag[16], fragX[2];
    f32x4 biasv[4], biasX;
    const f32x4 zero4 = {0.f, 0.f, 0.f, 0.f};

    if (isA) {
        #pragma unroll
        for (int g = 0; g < 4; ++g) {           // layer0 gates: 3 INDEPENDENT chunks
            const int r0 = g * HH + 16 * w + n; // gate row (i,f,g,o stacked)
            frag[g * 3 + 0] = mk(Whh0, r0, HH, 0,  HH, true);
            frag[g * 3 + 1] = mk(Whh0, r0, HH, 32, HH, true);
            frag[g * 3 + 2] = mk(Wih0, r0, II, 0,  II, true);  // x-chunk (k>=6 zero)
            biasv[g] = splat(b0[r0]);
        }
        const int rf = 16 * w + n;              // FC1 row
        fragX[0] = mk(W1, rf, HH, 0,  HH, true);
        fragX[1] = mk(W1, rf, HH, 32, HH, true);
        biasX = splat(bf1[rf]);
        #pragma unroll
        for (int i = 12; i < 16; ++i) frag[i] = frag[0];   // unused
    } else {
        #pragma unroll
        for (int g = 0; g < 4; ++g) {           // layer1 gates: 4 INDEPENDENT chunks
            const int r0 = g * HH + 16 * w + n;
            frag[g * 4 + 0] = mk(Wih1, r0, HH, 0,  HH, true);   // @ h0[t-2]
            frag[g * 4 + 1] = mk(Wih1, r0, HH, 32, HH, true);
            frag[g * 4 + 2] = mk(Whh1, r0, HH, 0,  HH, true);   // @ h1[t-3]
            frag[g * 4 + 3] = mk(Whh1, r0, HH, 32, HH, true);
            biasv[g] = splat(b1[r0]);
        }
        fragX[0] = mk(W2, n, HH, 0,  HH, n < OO);               // FC2 (w0 only uses)
        fragX[1] = mk(W2, n, HH, 32, HH, n < OO);
        biasX = splat((n < OO) ? bf2[n] : 0.f);
    }

    // x is register-carried; opaque VGPR pointer forces vector (vmcnt) loads
    const float* xrow = x + (size_t)row * TT * II;
    {
        unsigned long long p = (unsigned long long)xrow;
        asm volatile("" : "+v"(p));
        xrow = (const float*)p;
    }
    f32x4 xc03 = {0.f, 0.f, 0.f, 0.f};
    f32x2 xc45 = {0.f, 0.f};
    if (isA) {
        xc03 = *reinterpret_cast<const f32x4*>(xrow);
        xc45 = *reinterpret_cast<const f32x2*>(xrow + 4);
    }

    float* outrow = out + (size_t)row * TT * OO;
    float cst = 0.f;   // cell state: A lanes 0-15 hold c0[unit 16w+n]; B: c1

    __syncthreads();   // full barrier once, before the loop

    // pipeline: A@t: layer0 step t (h0[t-1]) + FC1 s3=t-3 (h1[t-3], Rb write)
    //           B@t: layer1 step s2=t-2 (h0[t-2], h1[t-3]) + FC2 s4=t-4 (Rb read)
    for (int t = 0; t <= TT + 3; ++t) {
        const int slp2 = (t + 1) & 1;   // h1[t-3] slot; Rb write slot
        const int slc2 = t & 1;         // h1 write slot (s2); Rb read slot (s4)

        if (isA) {
            // issue x[t+1] prefetch FIRST (vmcnt-lazy, ~1 iter of cover)
            const int tn = (t + 1 < TT) ? t + 1 : TT - 1;
            const float* xp = xrow + (size_t)tn * II;
            f32x4 xn03 = *reinterpret_cast<const f32x4*>(xp);
            f32x2 xn45 = *reinterpret_cast<const f32x2*>(xp + 4);

            // broadcast A-frags: h0[t-1] + FC1's h1[t-3] (issue all reads together)
            const f16x8 a0  = *reinterpret_cast<const f16x8*>(&H0[(t + 3) & 3][8 * q]);
            const f16x8 a1  = *reinterpret_cast<const f16x8*>(&H0[(t + 3) & 3][32 + 8 * q]);
            const f16x8 b0f = *reinterpret_cast<const f16x8*>(&H1[slp2][8 * q]);
            const f16x8 b1f = *reinterpret_cast<const f16x8*>(&H1[slp2][32 + 8 * q]);
            f16x8 a2;    // x[t] from regs (k>=6 zero on B-side)
            a2[0] = (_Float16)xc03[0]; a2[1] = (_Float16)xc03[1];
            a2[2] = (_Float16)xc03[2]; a2[3] = (_Float16)xc03[3];
            a2[4] = (_Float16)xc45[0]; a2[5] = (_Float16)xc45[1];
            a2[6] = (_Float16)0.f;     a2[7] = (_Float16)0.f;

            // 12 INDEPENDENT gate MFMAs + 2 independent FC1 MFMAs; scalar-sum at end
            float gv[4];
            #pragma unroll
            for (int g = 0; g < 4; ++g) {
                f32x4 acc0 = MFMA(a0, frag[g * 3 + 0], biasv[g]);
                f32x4 acc1 = MFMA(a1, frag[g * 3 + 1], zero4);
                f32x4 acc2 = MFMA(a2, frag[g * 3 + 2], zero4);
                gv[g] = (acc0[0] + acc1[0]) + acc2[0];
            }
            f32x4 f0 = MFMA(b0f, fragX[0], biasX);
            f32x4 f1 = MFMA(b1f, fragX[1], zero4);

            if (t < TT) {
                float i_ = fast_sig(gv[0]), f_ = fast_sig(gv[1]);
                float g_ = fast_tanh(gv[2]), o_ = fast_sig(gv[3]);
                cst = f_ * cst + i_ * g_;
                float h = o_ * fast_tanh(cst);
                if (lane < 16) H0[t & 3][16 * w + lane] = (_Float16)h;
            }
            {   // FC1: relu(W1 . h1[s3] + bf1) -> Rb
                const int s3 = t - 3;
                if (s3 >= 0 && s3 < TT && lane < 16)
                    Rb[slp2][16 * w + lane] = (_Float16)fmaxf(f0[0] + f1[0], 0.f);
            }
            xc03 = xn03;   // vmcnt wait lands at a2-build next iter
            xc45 = xn45;
        } else {
            const int s2 = t - 2, s4 = t - 4;
            // fused layer1: (b1) + Wih1.h0[s2] + Whh1.h1[s2-1] — 16 INDEPENDENT MFMAs
            const f16x8 h00 = *reinterpret_cast<const f16x8*>(&H0[(t + 2) & 3][8 * q]);
            const f16x8 h01 = *reinterpret_cast<const f16x8*>(&H0[(t + 2) & 3][32 + 8 * q]);
            const f16x8 a0  = *reinterpret_cast<const f16x8*>(&H1[slp2][8 * q]);
            const f16x8 a1  = *reinterpret_cast<const f16x8*>(&H1[slp2][32 + 8 * q]);
            const f16x8 r0  = *reinterpret_cast<const f16x8*>(&Rb[slc2][8 * q]);
            const f16x8 r1  = *reinterpret_cast<const f16x8*>(&Rb[slc2][32 + 8 * q]);

            float gv[4];
            #pragma unroll
            for (int g = 0; g < 4; ++g) {
                f32x4 acc0 = MFMA(h00, frag[g * 4 + 0], biasv[g]);
                f32x4 acc1 = MFMA(h01, frag[g * 4 + 1], zero4);
                f32x4 acc2 = MFMA(a0,  frag[g * 4 + 2], zero4);
                f32x4 acc3 = MFMA(a1,  frag[g * 4 + 3], zero4);
                gv[g] = (acc0[0] + acc1[0]) + (acc2[0] + acc3[0]);
            }
            f32x4 f0 = MFMA(r0, fragX[0], biasX);   // FC2 (only w==0's result used)
            f32x4 f1 = MFMA(r1, fragX[1], zero4);

            if (s2 >= 0 && s2 < TT) {
                float i_ = fast_sig(gv[0]), f_ = fast_sig(gv[1]);
                float g_ = fast_tanh(gv[2]), o_ = fast_sig(gv[3]);
                cst = f_ * cst + i_ * g_;
                float h = o_ * fast_tanh(cst);
                if (lane < 16) H1[slc2][16 * w + lane] = (_Float16)h;
            }
            if (w == 0 && s4 >= 0 && s4 < TT && lane < OO)
                outrow[(size_t)s4 * OO + lane] = f0[0] + f1[0];
        }
        LGKM_BARRIER();   // LDS-only drain; global ops stay in flight
    }
}

extern "C" void kernel_launch(void* const* d_in, const int* in_sizes, int n_in,
                              void* d_out, int out_size, void* d_ws, size_t ws_size,
                              hipStream_t stream) {
    const float* xp   = (const float*)d_in[0];
    const float* Wih0 = (const float*)d_in[1];
    const float* Whh0 = (const float*)d_in[2];
    const float* b0   = (const float*)d_in[3];
    const float* Wih1 = (const float*)d_in[4];
    const float* Whh1 = (const float*)d_in[5];
    const float* b1   = (const float*)d_in[6];
    const float* W1   = (const float*)d_in[7];
    const float* bf1  = (const float*)d_in[8];
    const float* W2   = (const float*)d_in[9];
    const float* bf2  = (const float*)d_in[10];
    float* outp = (float*)d_out;

    lstm_mfma_kernel<<<dim3(256), dim3(NTHR), 0, stream>>>(
        xp, Wih0, Whh0, b0, Wih1, Whh1, b1, W1, bf1, W2, bf2, outp);
}